// Round 16
// baseline (294.470 us; speedup 1.0000x reference)
//
#include <hip/hip_runtime.h>

typedef float floatx16 __attribute__((ext_vector_type(16)));
typedef __bf16 bf16x8 __attribute__((ext_vector_type(8)));
using u16 = unsigned short;
using u32 = unsigned int;

#define GLOBAL_AS __attribute__((address_space(1)))
#define LDS_AS    __attribute__((address_space(3)))

__device__ __forceinline__ u32 rne_bf16(float f) {
  u32 u = __float_as_uint(f);
  return (u + 0x7FFFu + ((u >> 16) & 1u)) >> 16;  // RNE
}

// ---------------- A: fp32 -> bf16, tile-permuted for 32x32x16 frags (R10) ----------------
__global__ __launch_bounds__(256) void cvt_x_perm(const float* __restrict__ x,
                                                  u16* __restrict__ xb, int K) {
  __shared__ u16 sm[16384];
  const int tid = threadIdx.x;
  const int Kt = K >> 6;
  const int pn = blockIdx.x / Kt, tt = blockIdx.x % Kt;
  const float* src = x + (size_t)pn * 256 * K + tt * 64;
#pragma unroll
  for (int j = 0; j < 16; ++j) {
    const int fc = j * 256 + tid;
    const int row = fc >> 4, kl4 = fc & 15;
    const float4 v = *(const float4*)(src + (size_t)row * K + kl4 * 4);
    uint2 o;
    o.x = rne_bf16(v.x) | (rne_bf16(v.y) << 16);
    o.y = rne_bf16(v.z) | (rne_bf16(v.w) << 16);
    const int gi = row >> 5, rowin = row & 31;
    const int ks = kl4 >> 2;
    const int lane = rowin + 32 * ((kl4 >> 1) & 1);
    const int e4 = (kl4 & 1) * 4;
    *(uint2*)(sm + gi * 2048 + ks * 512 + lane * 8 + e4) = o;
  }
  __syncthreads();
  u16* dst = xb + (size_t)pn * 256 * K + (size_t)tt * 16384;
#pragma unroll
  for (int j = 0; j < 8; ++j) {
    const int o = (j * 256 + tid) * 8;
    *(uint4*)(dst + o) = *(const uint4*)(sm + o);
  }
}

// ---- B: fp32 -> ternary bf16, per-(panel,wc,tile) frag-linear for DIRECT reg loads ----
// Layout: wb + ((pn*4 + wc)*Kt + tt)*4096 + f*512 + l*8 + e  (u16), where
// n = pn*256 + wc*64 + (f>>2)*32 + (l&31); k = tt*64 + (f&3)*16 + (l>>5)*8 + e.
// A wave's B-frag (ng,ks) load is base + (ng*4+ks)*512 + l*8 -> one coalesced
// 1KB global_load_dwordx4 (operand layout col=l&31, k=(l>>5)*8+j, R10-verified).
__global__ __launch_bounds__(256) void quant_w_permB(const float* __restrict__ w,
                                                     u16* __restrict__ wb, int K) {
  __shared__ u16 sm[16384];
  const int tid = threadIdx.x;
  const int Kt = K >> 6;
  const int pn = blockIdx.x / Kt, tt = blockIdx.x % Kt;
  const float* src = w + (size_t)pn * 256 * K + tt * 64;
#pragma unroll
  for (int j = 0; j < 16; ++j) {
    const int fc = j * 256 + tid;
    const int row = fc >> 4, kl4 = fc & 15;   // row 0..255, kl4 = k/4 (0..15)
    const float4 v = *(const float4*)(src + (size_t)row * K + kl4 * 4);
    float vv[4] = {v.x, v.y, v.z, v.w};
    u32 r[4];
#pragma unroll
    for (int e = 0; e < 4; ++e)
      r[e] = (vv[e] > 0.05f) ? 0x3F80u : ((vv[e] < -0.05f) ? 0xBF80u : 0u);
    uint2 o;
    o.x = r[0] | (r[1] << 16);
    o.y = r[2] | (r[3] << 16);
    const int wc = row >> 6, ng = (row >> 5) & 1, cf = row & 31;
    const int ks = kl4 >> 2, hi = (kl4 >> 1) & 1, e4 = (kl4 & 1) * 4;
    const int f = ng * 4 + ks, l = cf + 32 * hi;
    *(uint2*)(sm + wc * 4096 + f * 512 + l * 8 + e4) = o;
  }
  __syncthreads();
#pragma unroll
  for (int j = 0; j < 8; ++j) {
    const int o16 = (j * 256 + tid) * 8;
    const int wco = o16 >> 12, inner = o16 & 4095;
    u16* dst = wb + ((size_t)(pn * 4 + wco) * Kt + tt) * 4096 + inner;
    *(uint4*)dst = *(const uint4*)(sm + o16);
  }
}

// ---------------- 256x256 BK=64 GEMM: A in LDS (64KB dbuf), B direct-to-reg bf16 ----------------
// LDS traffic cut 256->160 KB/tile (the R4/R11/R15-invariant binder at ~56B/cyc).
// Per tile: [A-stage(t+1)->bufo x4 gloads; sched_barrier] [af01+af23 reads x16]
// [Q0 m01xblo][Q1 m23xblo] -> bflo dead -> load Blo(t+1) (4x dwordx4, same regs)
// [Q2 m01xbhi][Q3 m23xbhi] -> load Bhi(t+1). End: vmcnt(8) drains exactly the
// A-stage (issue order pinned: A first, fenced; B loads cannot hoist above
// sched_barrier(0)); barrier publishes bufo (next tile's stage overwrites bufc,
// whose reads were consumed by this tile's MFMAs). B waits are compiler-counted.
__global__ __launch_bounds__(512, 2) void gemm_bin_breg2(
    const u16* __restrict__ Ap, const u16* __restrict__ Bp,
    const float* __restrict__ bias, float* __restrict__ C,
    int M, int N, int K) {
  __shared__ u16 lds[32768];  // 2 buf x 16384 u16 (A only) = 64 KiB

  const int tid = threadIdx.x;
  const int w = tid >> 6, l = tid & 63;
  const int wr = w >> 2, wc = w & 3;

  const int nbn = N >> 8;
  int wg = blockIdx.x;
  const int nwg = gridDim.x;
  if ((nwg & 7) == 0) wg = (wg & 7) * (nwg >> 3) + (wg >> 3);  // XCD swizzle (bijective)
  const int bm = wg / nbn, bn = wg % nbn;

  const int T = K >> 6;

  const u16* const Abase = Ap + (size_t)bm * ((size_t)K << 8) + tid * 8;
  const u16* const Bbase = Bp + ((size_t)(bn * 4 + wc) * T) * 4096 + l * 8;

  const u16* const afp0 = lds + wr * 8192 + l * 8;  // + m*2048 + ks*512

  floatx16 acc[4][2] = {};
  bf16x8 af[8], af2[8], bflo[4], bfhi[4];

#define GLOAD(gptr, u16off)                                                    \
  __builtin_amdgcn_global_load_lds((const GLOBAL_AS void*)(gptr),              \
                                   (LDS_AS void*)(lds + (u16off)), 16, 0, 0)
#define ASTAGE(tt, bufdst)                                                     \
  {                                                                            \
    const size_t tb_ = (size_t)(tt) * 16384;                                   \
    GLOAD(Abase + tb_ + 0 * 4096, (bufdst) + 0 + tid * 8);                     \
    GLOAD(Abase + tb_ + 1 * 4096, (bufdst) + 4096 + tid * 8);                  \
    GLOAD(Abase + tb_ + 2 * 4096, (bufdst) + 8192 + tid * 8);                  \
    GLOAD(Abase + tb_ + 3 * 4096, (bufdst) + 12288 + tid * 8);                 \
  }

  // prologue: A(0)->buf0 (first, so vmcnt(8) semantics hold), then B(0) x8
  ASTAGE(0, 0)
  __builtin_amdgcn_sched_barrier(0);
#pragma unroll
  for (int ks = 0; ks < 4; ++ks)
    bflo[ks] = *(const bf16x8*)(Bbase + ks * 512);
#pragma unroll
  for (int ks = 0; ks < 4; ++ks)
    bfhi[ks] = *(const bf16x8*)(Bbase + (4 + ks) * 512);
  asm volatile("s_waitcnt vmcnt(8)\ns_barrier" ::: "memory");  // A(0) landed; B drains under tile 0

  for (int t = 0; t < T; ++t) {
    const int bufc = (t & 1) << 14;
    const int bufo = bufc ^ 16384;
    const bool st1 = (t + 1 < T);
    const u16* afp = afp0 + bufc;
    const u16* Bnext = Bbase + (size_t)(t + 1) * 4096;

    if (st1) ASTAGE(t + 1, bufo)
    __builtin_amdgcn_sched_barrier(0);  // pin A-stage at top; B loads can't hoist above

    // all A fragment reads (compiler inserts counted lgkm before each quadrant)
#pragma unroll
    for (int m = 0; m < 2; ++m)
#pragma unroll
      for (int ks = 0; ks < 4; ++ks)
        af[m * 4 + ks] = *(const bf16x8*)(afp + m * 2048 + ks * 512);
#pragma unroll
    for (int m = 0; m < 2; ++m)
#pragma unroll
      for (int ks = 0; ks < 4; ++ks)
        af2[m * 4 + ks] = *(const bf16x8*)(afp + 4096 + m * 2048 + ks * 512);

    // Q0: (m0,m1) x blo ; Q1: (m2,m3) x blo  -> bflo dead
#pragma unroll
    for (int ks = 0; ks < 4; ++ks)
#pragma unroll
      for (int m = 0; m < 2; ++m)
        acc[m][0] = __builtin_amdgcn_mfma_f32_32x32x16_bf16(
            af[m * 4 + ks], bflo[ks], acc[m][0], 0, 0, 0);
#pragma unroll
    for (int ks = 0; ks < 4; ++ks)
#pragma unroll
      for (int m = 0; m < 2; ++m)
        acc[2 + m][0] = __builtin_amdgcn_mfma_f32_32x32x16_bf16(
            af2[m * 4 + ks], bflo[ks], acc[2 + m][0], 0, 0, 0);

    if (st1) {
#pragma unroll
      for (int ks = 0; ks < 4; ++ks)
        bflo[ks] = *(const bf16x8*)(Bnext + ks * 512);  // Blo(t+1), ~2-quadrant lead
      __builtin_amdgcn_sched_barrier(0);                // don't sink below Q2/Q3
    }

    // Q2: (m0,m1) x bhi ; Q3: (m2,m3) x bhi  -> bfhi dead
#pragma unroll
    for (int ks = 0; ks < 4; ++ks)
#pragma unroll
      for (int m = 0; m < 2; ++m)
        acc[m][1] = __builtin_amdgcn_mfma_f32_32x32x16_bf16(
            af[m * 4 + ks], bfhi[ks], acc[m][1], 0, 0, 0);
#pragma unroll
    for (int ks = 0; ks < 4; ++ks)
#pragma unroll
      for (int m = 0; m < 2; ++m)
        acc[2 + m][1] = __builtin_amdgcn_mfma_f32_32x32x16_bf16(
            af2[m * 4 + ks], bfhi[ks], acc[2 + m][1], 0, 0, 0);

    if (st1) {
#pragma unroll
      for (int ks = 0; ks < 4; ++ks)
        bfhi[ks] = *(const bf16x8*)(Bnext + (4 + ks) * 512);  // Bhi(t+1)
      // vmcnt(8): outstanding = A-stage(4,oldest) + Blo(4) + Bhi(4);
      // drains exactly the A-stage -> bufo published by the barrier.
      asm volatile("s_waitcnt vmcnt(8)\ns_barrier" ::: "memory");
    }
  }
#undef ASTAGE
#undef GLOAD

  // ---- epilogue: C/D col=l&31, row=(q&3)+8*(q>>2)+4*(l>>5) (m74/m101-verified) ----
  const int colq = l & 31;
  const int hi4 = (l >> 5) * 4;
#pragma unroll
  for (int m = 0; m < 4; ++m) {
    const int rowb = bm * 256 + wr * 128 + m * 32 + hi4;
#pragma unroll
    for (int n = 0; n < 2; ++n) {
      const int col = bn * 256 + wc * 64 + n * 32 + colq;
      const float bv = bias[col];
      float* cp = C + (size_t)rowb * N + col;
#pragma unroll
      for (int q = 0; q < 16; ++q) {
        const int dr = (q & 3) + 8 * (q >> 2);
        cp[(size_t)dr * N] = acc[m][n][q] + bv;
      }
    }
  }
}

// ---------------- fallback: slow but correct ----------------
__global__ void gemm_naive_kernel(const float* __restrict__ x, const float* __restrict__ wgt,
                                  const float* __restrict__ bias, float* __restrict__ out,
                                  int M, int N, int K) {
  long long idx = (long long)blockIdx.x * blockDim.x + threadIdx.x;
  if (idx >= (long long)M * N) return;
  int o = (int)(idx % N);
  int m = (int)(idx / N);
  const float* xr = x + (size_t)m * K;
  const float* wr = wgt + (size_t)o * K;
  float s = 0.f;
  for (int i = 0; i < K; ++i) {
    float wv = wr[i];
    float t = (wv > 0.05f) ? 1.f : ((wv < -0.05f) ? -1.f : 0.f);
    s = fmaf(xr[i], t, s);
  }
  out[idx] = s + bias[o];
}

extern "C" void kernel_launch(void* const* d_in, const int* in_sizes, int n_in,
                              void* d_out, int out_size, void* d_ws, size_t ws_size,
                              hipStream_t stream) {
  const float* x    = (const float*)d_in[0];
  const float* wgt  = (const float*)d_in[1];
  const float* bias = (const float*)d_in[2];
  float* out = (float*)d_out;

  const int N = in_sizes[2];                 // out features
  const int K = in_sizes[1] / N;             // in features
  const int M = in_sizes[0] / K;             // batch rows

  const size_t need = ((size_t)M * K + (size_t)N * K) * sizeof(u16);
  if (ws_size >= need && (M % 256 == 0) && (N % 256 == 0) && (K % 64 == 0) && K >= 192) {
    u16* xb = (u16*)d_ws;
    u16* wb = xb + (size_t)M * K;
    const int Kt = K / 64;
    cvt_x_perm<<<(M / 256) * Kt, 256, 0, stream>>>(x, xb, K);
    quant_w_permB<<<(N / 256) * Kt, 256, 0, stream>>>(wgt, wb, K);
    const int grid = (M / 256) * (N / 256);
    gemm_bin_breg2<<<grid, 512, 0, stream>>>(xb, wb, bias, out, M, N, K);
  } else {
    const long long total = (long long)M * N;
    gemm_naive_kernel<<<(unsigned)((total + 255) / 256), 256, 0, stream>>>(x, wgt, bias, out, M, N, K);
  }
}